// Round 5
// baseline (504.667 us; speedup 1.0000x reference)
//
#include <hip/hip_runtime.h>
#include <hip/hip_bf16.h>

typedef __bf16 bf16x8 __attribute__((ext_vector_type(8)));
typedef float  f32x4  __attribute__((ext_vector_type(4)));
typedef short  short4v __attribute__((ext_vector_type(4)));

#define B_SZ   2
#define T_SEQ  2048
#define C_EMB  2048
#define NH     16
#define HD     128
#define M_ROWS (B_SZ * T_SEQ)   /* 4096 */
#define N_QKV  (3 * C_EMB)      /* 6144 */
#define LQK    (2 * C_EMB)      /* 4096: qk buffer row length (q|k columns) */

static __device__ __forceinline__ unsigned short f2b(float f) {
  union { __hip_bfloat16 h; unsigned short u; } cv;
  cv.h = __float2bfloat16(f);
  return cv.u;
}
static __device__ __forceinline__ void store_out(float* p, float v) { *p = v; }
static __device__ __forceinline__ void store_out(unsigned short* p, float v) { *p = f2b(v); }

static __device__ __forceinline__ ushort4 load4_bf16(const float* p) {
  float4 v = *(const float4*)p;
  ushort4 o; o.x = f2b(v.x); o.y = f2b(v.y); o.z = f2b(v.z); o.w = f2b(v.w);
  return o;
}
static __device__ __forceinline__ ushort4 load4_bf16(const unsigned short* p) {
  return *(const ushort4*)p;
}

// async global->LDS, 16B/lane; LDS dest must be wave-uniform base + lane*16
static __device__ __forceinline__ void async_cp16(const unsigned short* g, unsigned short* l) {
  __builtin_amdgcn_global_load_lds((__attribute__((address_space(1))) void*)(g),
                                   (__attribute__((address_space(3))) void*)(l), 16, 0, 0);
}

// ---------------------------------------------------------------------------
// Shared epilogue. MODE 0: C[row][col] = acc + bias (OutT).
// MODE 1 (qkv split): cols [0,4096) -> qk bf16 (row-major, ld 4096);
//                     cols [4096,6144) -> vt bf16 [(b*NH+h)*HD+d][t]  (V^T).
// ---------------------------------------------------------------------------
template <int MODE, typename OutT>
static __device__ __forceinline__ void gemm_epilogue(
    f32x4 (&acc)[4][4], const float* __restrict__ bias,
    OutT* __restrict__ C, int ldc,
    unsigned short* __restrict__ qk, unsigned short* __restrict__ vt,
    int bm0, int bn0, int wm, int wn, int ln, int lq) {
  #pragma unroll
  for (int i = 0; i < 4; ++i) {
    const int row0 = bm0 + wm * 64 + i * 16 + lq * 4;
    #pragma unroll
    for (int j = 0; j < 4; ++j) {
      const int col = bn0 + wn * 64 + j * 16 + ln;
      const float bv = bias[col];
      if constexpr (MODE == 0) {
        #pragma unroll
        for (int r = 0; r < 4; ++r)
          store_out(&C[(size_t)(row0 + r) * ldc + col], acc[i][j][r] + bv);
      } else {
        if (bn0 < 2 * C_EMB) {  // q or k columns (wave-uniform per block)
          #pragma unroll
          for (int r = 0; r < 4; ++r)
            qk[(size_t)(row0 + r) * LQK + col] = f2b(acc[i][j][r] + bv);
        } else {                // v columns -> transposed store
          const int c2 = col - 2 * C_EMB;           // h*128 + d
          const int bb = row0 >> 11;                // batch
          const int t0 = row0 & (T_SEQ - 1);
          const int vrow = (bb * NH + (c2 >> 7)) * HD + (c2 & 127);
          ushort4 p;
          p.x = f2b(acc[i][j][0] + bv); p.y = f2b(acc[i][j][1] + bv);
          p.z = f2b(acc[i][j][2] + bv); p.w = f2b(acc[i][j][3] + bv);
          *(ushort4*)(vt + (size_t)vrow * T_SEQ + t0) = p;  // t0 % 4 == 0
        }
      }
    }
  }
}

// ---------------------------------------------------------------------------
// Tier A GEMM (m97 structure): C = A[M,K](bf16, lda) * Bt[N,K]^T(bf16) + bias.
// ---------------------------------------------------------------------------
template <int MODE, typename OutT>
__global__ __launch_bounds__(256) void gemm_bt(const unsigned short* __restrict__ A, int lda,
                                               const unsigned short* __restrict__ Bt,
                                               const float* __restrict__ bias,
                                               OutT* __restrict__ C, int ldc,
                                               unsigned short* __restrict__ qk,
                                               unsigned short* __restrict__ vt,
                                               int N, int K) {
  __shared__ __align__(16) unsigned short As[128 * 32];
  __shared__ __align__(16) unsigned short Bs[128 * 32];
  const int tid = threadIdx.x;
  const int wave = tid >> 6, lane = tid & 63;
  const int wm = wave >> 1, wn = wave & 1;
  const int ln = lane & 15, lq = lane >> 4;
  const int bm0 = blockIdx.y * 128, bn0 = blockIdx.x * 128;

  f32x4 acc[4][4];
  #pragma unroll
  for (int i = 0; i < 4; ++i)
    #pragma unroll
    for (int j = 0; j < 4; ++j) acc[i][j] = (f32x4){0.f, 0.f, 0.f, 0.f};

  const unsigned short* Ag = A  + (size_t)(bm0 + wave * 32 + (lane >> 2)) * lda + (lane & 3) * 8;
  const unsigned short* Bg = Bt + (size_t)(bn0 + wave * 32 + (lane >> 2)) * K   + (lane & 3) * 8;
  unsigned short* Al = As + wave * 1024 + lane * 8;
  unsigned short* Bl = Bs + wave * 1024 + lane * 8;

  for (int k0 = 0; k0 < K; k0 += 32) {
    async_cp16(Ag + k0, Al);
    async_cp16(Ag + k0 + 16 * lda, Al + 512);
    async_cp16(Bg + k0, Bl);
    async_cp16(Bg + k0 + 16 * K, Bl + 512);
    __syncthreads();
    bf16x8 af[4], bfv[4];
    #pragma unroll
    for (int i = 0; i < 4; ++i) {
      af[i]  = *(const bf16x8*)(As + (wm * 64 + i * 16 + ln) * 32 + lq * 8);
      bfv[i] = *(const bf16x8*)(Bs + (wn * 64 + i * 16 + ln) * 32 + lq * 8);
    }
    #pragma unroll
    for (int i = 0; i < 4; ++i)
      #pragma unroll
      for (int j = 0; j < 4; ++j)
        acc[i][j] = __builtin_amdgcn_mfma_f32_16x16x32_bf16(af[i], bfv[j], acc[i][j], 0, 0, 0);
    __syncthreads();
  }
  gemm_epilogue<MODE, OutT>(acc, bias, C, ldc, qk, vt, bm0, bn0, wm, wn, ln, lq);
}

// ---------------------------------------------------------------------------
// Tier B GEMM fallback (validated round-2 structure).
// ---------------------------------------------------------------------------
template <int MODE, typename AT, typename OutT>
__global__ __launch_bounds__(256) void gemm_any(const AT* __restrict__ A, int lda,
                                                const float* __restrict__ B, int ldb,
                                                const float* __restrict__ bias,
                                                OutT* __restrict__ C, int ldc,
                                                unsigned short* __restrict__ qk,
                                                unsigned short* __restrict__ vt,
                                                int N, int K) {
  __shared__ __align__(16) unsigned short As[128 * 32];
  __shared__ __align__(16) unsigned short Bs[128 * 32];
  __shared__ __align__(16) float Bstage[32 * 132];

  const int tid = threadIdx.x;
  const int wave = tid >> 6, lane = tid & 63;
  const int wm = wave >> 1, wn = wave & 1;
  const int ln = lane & 15, lq = lane >> 4;
  const int bm0 = blockIdx.y * 128, bn0 = blockIdx.x * 128;

  f32x4 acc[4][4];
  #pragma unroll
  for (int i = 0; i < 4; ++i)
    #pragma unroll
    for (int j = 0; j < 4; ++j) acc[i][j] = (f32x4){0.f, 0.f, 0.f, 0.f};

  for (int k0 = 0; k0 < K; k0 += 32) {
    #pragma unroll
    for (int j = 0; j < 4; ++j) {
      const int item = tid + j * 256;
      const int m = item >> 3;
      const int kf = (item & 7) * 4;
      *(ushort4*)(As + m * 32 + kf) = load4_bf16(A + (size_t)(bm0 + m) * lda + k0 + kf);
    }
    #pragma unroll
    for (int j = 0; j < 4; ++j) {
      const int item = tid + j * 256;
      const int kr = item >> 5;
      const int nf = (item & 31) * 4;
      *(float4*)(Bstage + kr * 132 + nf) =
          *(const float4*)(B + (size_t)(k0 + kr) * ldb + bn0 + nf);
    }
    __syncthreads();
    #pragma unroll
    for (int j = 0; j < 4; ++j) {
      const int item = tid + j * 256;
      const int n = item >> 3;
      const int kq = item & 7;
      const int k = kq * 4;
      ushort4 h4;
      h4.x = f2b(Bstage[(k + 0) * 132 + n]);
      h4.y = f2b(Bstage[(k + 1) * 132 + n]);
      h4.z = f2b(Bstage[(k + 2) * 132 + n]);
      h4.w = f2b(Bstage[(k + 3) * 132 + n]);
      *(ushort4*)(Bs + n * 32 + (((kq >> 1) ^ (n & 3)) << 3) + ((kq & 1) << 2)) = h4;
    }
    __syncthreads();
    bf16x8 af[4], bfv[4];
    #pragma unroll
    for (int i = 0; i < 4; ++i) {
      af[i] = *(const bf16x8*)(As + (wm * 64 + i * 16 + ln) * 32 + lq * 8);
      const int n = wn * 64 + i * 16 + ln;
      bfv[i] = *(const bf16x8*)(Bs + n * 32 + ((lq ^ (n & 3)) << 3));
    }
    #pragma unroll
    for (int i = 0; i < 4; ++i)
      #pragma unroll
      for (int j = 0; j < 4; ++j)
        acc[i][j] = __builtin_amdgcn_mfma_f32_16x16x32_bf16(af[i], bfv[j], acc[i][j], 0, 0, 0);
    __syncthreads();
  }
  gemm_epilogue<MODE, OutT>(acc, bias, C, ldc, qk, vt, bm0, bn0, wm, wn, ln, lq);
}

// ---------------------------------------------------------------- prep (Tier A)
__global__ __launch_bounds__(256) void cast_x_bf16(const float4* __restrict__ in,
                                                   ushort4* __restrict__ out, int n4) {
  int i = blockIdx.x * 256 + threadIdx.x;
  if (i < n4) {
    float4 v = in[i];
    ushort4 o; o.x = f2b(v.x); o.y = f2b(v.y); o.z = f2b(v.z); o.w = f2b(v.w);
    out[i] = o;
  }
}

__global__ __launch_bounds__(256) void transpose_cast(const float* __restrict__ in,
                                                      unsigned short* __restrict__ out,
                                                      int R, int Cc) {
  __shared__ float t[32][33];
  const int bx = blockIdx.x * 32, by = blockIdx.y * 32;
  const int tx = threadIdx.x & 31, ty = threadIdx.x >> 5;
  #pragma unroll
  for (int j = 0; j < 32; j += 8)
    t[ty + j][tx] = in[(size_t)(by + ty + j) * Cc + bx + tx];
  __syncthreads();
  #pragma unroll
  for (int j = 0; j < 32; j += 8)
    out[(size_t)(bx + ty + j) * R + by + tx] = f2b(t[tx][ty + j]);
}

// ---------------------------------------------------------------------------
// Flash attention, transposed-S, max-free softmax, double-Q blocks.
// grid (16, NH, B), block 256 = 4 waves. Block j=15-bx owns 128 queries
// [128j, 128j+128) as two 64-query tiles A (low) and B (high); wave w owns
// 16 queries of each. Per 64-key iteration:
//   S^T = K Q^T (ak fragments from LDS shared by both tiles),
//   p = exp2(s*const) (NO max tracking: scores bounded, fp32 can't overflow;
//     per-lane l accumulation, single cross-lane reduce after the loop),
//   O^T += V^T P^T via K=16 MFMA with P straight from registers.
// Mask only on each tile's diagonal iteration (zero p post-exp).
// y written into the q-columns of qk (race-free as before).
// ---------------------------------------------------------------------------
__global__ __launch_bounds__(256, 2) void attn_st(unsigned short* __restrict__ qk,
                                                  const unsigned short* __restrict__ vt) {
  __shared__ __align__(16) unsigned short Ks[64 * 136];   // K tile [key][d], pad 136
  __shared__ __align__(16) unsigned short VTs[128 * 72];  // V^T tile [d][key], pad 72

  const int tid = threadIdx.x;
  const int w = tid >> 6, lane = tid & 63;
  const int ln = lane & 15, lq = lane >> 4;
  const int j = 15 - (int)blockIdx.x;     // longest blocks dispatched first
  const int qb0 = j * 128;
  const int h = blockIdx.y, b = blockIdx.z;
  // 1/sqrt(128) * log2(e)  (scale folded into exp2 argument)
  const float EXPSC = 0.08838834764831845f * 1.4426950408889634f;

  // Q fragments for both tiles (B-operand: n=ln=query, k=lq*8..)
  const int qgA = qb0 + w * 16 + ln;
  const int qgB = qgA + 64;
  const unsigned short* QpA = qk + (size_t)(b * T_SEQ + qgA) * LQK + h * HD + lq * 8;
  bf16x8 bqA[4], bqB[4];
  #pragma unroll
  for (int ks = 0; ks < 4; ++ks) {
    bqA[ks] = *(const bf16x8*)(QpA + ks * 32);
    bqB[ks] = *(const bf16x8*)(QpA + (size_t)64 * LQK + ks * 32);
  }

  f32x4 otA[8], otB[8];
  #pragma unroll
  for (int dt = 0; dt < 8; ++dt) {
    otA[dt] = (f32x4){0.f, 0.f, 0.f, 0.f};
    otB[dt] = (f32x4){0.f, 0.f, 0.f, 0.f};
  }
  float lA = 0.f, lB = 0.f;

  const int kbmax = 2 * j + 1;
  for (int kb = 0; kb <= kbmax; ++kb) {
    __syncthreads();  // prev iter's LDS reads complete
    #pragma unroll
    for (int jj = 0; jj < 4; ++jj) {        // K tile: 64 keys x 128 d
      const int s = tid + jj * 256;
      const int row = s >> 4, c8 = s & 15;
      *(uint4*)(Ks + row * 136 + c8 * 8) =
          *(const uint4*)(qk + (size_t)(b * T_SEQ + kb * 64 + row) * LQK + C_EMB + h * HD + c8 * 8);
    }
    #pragma unroll
    for (int jj = 0; jj < 4; ++jj) {        // V^T tile: 128 d x 64 keys
      const int s = tid + jj * 256;
      const int row = s >> 3, c8 = s & 7;
      *(uint4*)(VTs + row * 72 + c8 * 8) =
          *(const uint4*)(vt + ((size_t)(b * NH + h) * HD + row) * T_SEQ + kb * 64 + c8 * 8);
    }
    __syncthreads();

    const bool actA = (kb < kbmax);         // tile A active (block-uniform)
    const bool diagB = (kb == kbmax);
    const bool diagA = (kb == kbmax - 1);

    // ---- S^T = K Q^T : ak fragments shared by both tiles
    f32x4 stA[4], stB[4];
    if (actA) {
      #pragma unroll
      for (int kt = 0; kt < 4; ++kt) {
        stA[kt] = (f32x4){0.f, 0.f, 0.f, 0.f};
        stB[kt] = (f32x4){0.f, 0.f, 0.f, 0.f};
        #pragma unroll
        for (int ks = 0; ks < 4; ++ks) {
          bf16x8 ak = *(const bf16x8*)(Ks + (kt * 16 + ln) * 136 + ks * 32 + lq * 8);
          stB[kt] = __builtin_amdgcn_mfma_f32_16x16x32_bf16(ak, bqB[ks], stB[kt], 0, 0, 0);
          stA[kt] = __builtin_amdgcn_mfma_f32_16x16x32_bf16(ak, bqA[ks], stA[kt], 0, 0, 0);
        }
      }
    } else {
      #pragma unroll
      for (int kt = 0; kt < 4; ++kt) {
        stB[kt] = (f32x4){0.f, 0.f, 0.f, 0.f};
        #pragma unroll
        for (int ks = 0; ks < 4; ++ks) {
          bf16x8 ak = *(const bf16x8*)(Ks + (kt * 16 + ln) * 136 + ks * 32 + lq * 8);
          stB[kt] = __builtin_amdgcn_mfma_f32_16x16x32_bf16(ak, bqB[ks], stB[kt], 0, 0, 0);
        }
      }
    }

    // ---- max-free softmax: p = exp2(s*EXPSC), zero masked, accumulate l
    short4v pfA[4], pfB[4];
    #pragma unroll
    for (int kt = 0; kt < 4; ++kt)
      #pragma unroll
      for (int r = 0; r < 4; ++r) {
        float p = __builtin_exp2f(stB[kt][r] * EXPSC);
        if (diagB && (kb * 64 + kt * 16 + lq * 4 + r > qgB)) p = 0.f;
        lB += p;
        pfB[kt][r] = (short)f2b(p);
      }
    if (actA) {
      #pragma unroll
      for (int kt = 0; kt < 4; ++kt)
        #pragma unroll
        for (int r = 0; r < 4; ++r) {
          float p = __builtin_exp2f(stA[kt][r] * EXPSC);
          if (diagA && (kb * 64 + kt * 16 + lq * 4 + r > qgA)) p = 0.f;
          lA += p;
          pfA[kt][r] = (short)f2b(p);
        }
    }

    // ---- O^T += V^T P^T : av fragments shared by both tiles
    if (actA) {
      #pragma unroll
      for (int kt = 0; kt < 4; ++kt)
        #pragma unroll
        for (int dt = 0; dt < 8; ++dt) {
          short4v av = *(const short4v*)(VTs + (dt * 16 + ln) * 72 + kt * 16 + lq * 4);
          otB[dt] = __builtin_amdgcn_mfma_f32_16x16x16bf16_1k(av, pfB[kt], otB[dt], 0, 0, 0);
          otA[dt] = __builtin_amdgcn_mfma_f32_16x16x16bf16_1k(av, pfA[kt], otA[dt], 0, 0, 0);
        }
    } else {
      #pragma unroll
      for (int kt = 0; kt < 4; ++kt)
        #pragma unroll
        for (int dt = 0; dt < 8; ++dt) {
          short4v av = *(const short4v*)(VTs + (dt * 16 + ln) * 72 + kt * 16 + lq * 4);
          otB[dt] = __builtin_amdgcn_mfma_f32_16x16x16bf16_1k(av, pfB[kt], otB[dt], 0, 0, 0);
        }
    }
  }

  // ---- final l reduction across the 4 partner lanes (one time only)
  lA += __shfl_xor(lA, 16); lA += __shfl_xor(lA, 32);
  lB += __shfl_xor(lB, 16); lB += __shfl_xor(lB, 32);
  const float invA = 1.f / lA, invB = 1.f / lB;

  // ---- epilogue: O^T -> O via LDS (tile A into Ks area, tile B into VTs area)
  __syncthreads();
  #pragma unroll
  for (int dt = 0; dt < 8; ++dt) {
    ushort4 pa, pb;
    pa.x = f2b(otA[dt][0] * invA); pa.y = f2b(otA[dt][1] * invA);
    pa.z = f2b(otA[dt][2] * invA); pa.w = f2b(otA[dt][3] * invA);
    pb.x = f2b(otB[dt][0] * invB); pb.y = f2b(otB[dt][1] * invB);
    pb.z = f2b(otB[dt][2] * invB); pb.w = f2b(otB[dt][3] * invB);
    *(ushort4*)(Ks  + (w * 16 + ln) * 136 + dt * 16 + lq * 4) = pa;
    *(ushort4*)(VTs + (w * 16 + ln) * 136 + dt * 16 + lq * 4) = pb;
  }
  __syncthreads();
  #pragma unroll
  for (int jj = 0; jj < 4; ++jj) {
    const int s = tid + jj * 256;
    const int row = s >> 4, c8 = s & 15;
    *(uint4*)(qk + (size_t)(b * T_SEQ + qb0 + row) * LQK + h * HD + c8 * 8) =
        *(const uint4*)(Ks + row * 136 + c8 * 8);
    *(uint4*)(qk + (size_t)(b * T_SEQ + qb0 + 64 + row) * LQK + h * HD + c8 * 8) =
        *(const uint4*)(VTs + row * 136 + c8 * 8);
  }
}

// ---------------------------------------------------------------- launch
extern "C" void kernel_launch(void* const* d_in, const int* in_sizes, int n_in,
                              void* d_out, int out_size, void* d_ws, size_t ws_size,
                              hipStream_t stream) {
  (void)in_sizes; (void)n_in; (void)out_size;
  const float* x      = (const float*)d_in[0];
  const float* W_attn = (const float*)d_in[1];
  const float* b_attn = (const float*)d_in[2];
  const float* W_proj = (const float*)d_in[3];
  const float* b_proj = (const float*)d_in[4];
  float* out = (float*)d_out;

  char* ws = (char*)d_ws;
  unsigned short* qk = (unsigned short*)(ws);                  // 32 MiB [4096][4096]
  unsigned short* vt = (unsigned short*)(ws + 33554432);       // 16 MiB [B*NH*HD][T]
  unsigned short* xb  = (unsigned short*)(ws + 50331648);      // 16 MiB x bf16
  unsigned short* WaT = (unsigned short*)(ws + 67108864);      // 24 MiB W_attn^T bf16
  unsigned short* WpT = (unsigned short*)(ws + 92274688);      // 8  MiB W_proj^T bf16
  const bool tierA = (ws_size >= 100663296);                   // 96 MiB

  if (tierA) {
    const int n_x = M_ROWS * C_EMB;
    cast_x_bf16<<<n_x / 4 / 256, 256, 0, stream>>>((const float4*)x, (ushort4*)xb, n_x / 4);
    transpose_cast<<<dim3(N_QKV / 32, C_EMB / 32), 256, 0, stream>>>(W_attn, WaT, C_EMB, N_QKV);
    transpose_cast<<<dim3(C_EMB / 32, C_EMB / 32), 256, 0, stream>>>(W_proj, WpT, C_EMB, C_EMB);
    gemm_bt<1, unsigned short><<<dim3(N_QKV / 128, M_ROWS / 128), 256, 0, stream>>>(
        xb, C_EMB, WaT, b_attn, (unsigned short*)nullptr, 0, qk, vt, N_QKV, C_EMB);
  } else {
    gemm_any<1, float, unsigned short><<<dim3(N_QKV / 128, M_ROWS / 128), 256, 0, stream>>>(
        x, C_EMB, W_attn, N_QKV, b_attn, (unsigned short*)nullptr, 0, qk, vt, N_QKV, C_EMB);
  }

  attn_st<<<dim3(16, NH, B_SZ), 256, 0, stream>>>(qk, vt);

  if (tierA) {
    gemm_bt<0, float><<<dim3(C_EMB / 128, M_ROWS / 128), 256, 0, stream>>>(
        qk, LQK, WpT, b_proj, out, C_EMB, nullptr, nullptr, C_EMB, C_EMB);
  } else {
    gemm_any<0, unsigned short, float><<<dim3(C_EMB / 128, M_ROWS / 128), 256, 0, stream>>>(
        qk, LQK, W_proj, C_EMB, b_proj, out, C_EMB, nullptr, nullptr, C_EMB, C_EMB);
  }
}

// Round 6
// 424.666 us; speedup vs baseline: 1.1884x; 1.1884x over previous
//
#include <hip/hip_runtime.h>
#include <hip/hip_bf16.h>

typedef __bf16 bf16x8 __attribute__((ext_vector_type(8)));
typedef float  f32x4  __attribute__((ext_vector_type(4)));
typedef short  short4v __attribute__((ext_vector_type(4)));

#define B_SZ   2
#define T_SEQ  2048
#define C_EMB  2048
#define NH     16
#define HD     128
#define M_ROWS (B_SZ * T_SEQ)   /* 4096 */
#define N_QKV  (3 * C_EMB)      /* 6144 */
#define LQK    (2 * C_EMB)      /* 4096: qk buffer row length (q|k columns) */

static __device__ __forceinline__ unsigned short f2b(float f) {
  union { __hip_bfloat16 h; unsigned short u; } cv;
  cv.h = __float2bfloat16(f);
  return cv.u;
}
static __device__ __forceinline__ void store_out(float* p, float v) { *p = v; }
static __device__ __forceinline__ void store_out(unsigned short* p, float v) { *p = f2b(v); }

static __device__ __forceinline__ ushort4 load4_bf16(const float* p) {
  float4 v = *(const float4*)p;
  ushort4 o; o.x = f2b(v.x); o.y = f2b(v.y); o.z = f2b(v.z); o.w = f2b(v.w);
  return o;
}
static __device__ __forceinline__ ushort4 load4_bf16(const unsigned short* p) {
  return *(const ushort4*)p;
}

// async global->LDS, 16B/lane; LDS dest must be wave-uniform base + lane*16
static __device__ __forceinline__ void async_cp16(const unsigned short* g, unsigned short* l) {
  __builtin_amdgcn_global_load_lds((__attribute__((address_space(1))) void*)(g),
                                   (__attribute__((address_space(3))) void*)(l), 16, 0, 0);
}

// ---------------------------------------------------------------------------
// Shared epilogue. MODE 0: C[row][col] = acc + bias (OutT).
// MODE 1 (qkv split): cols [0,4096) -> qk bf16 (row-major, ld 4096);
//                     cols [4096,6144) -> vt bf16 [(b*NH+h)*HD+d][t]  (V^T).
// ---------------------------------------------------------------------------
template <int MODE, typename OutT>
static __device__ __forceinline__ void gemm_epilogue(
    f32x4 (&acc)[4][4], const float* __restrict__ bias,
    OutT* __restrict__ C, int ldc,
    unsigned short* __restrict__ qk, unsigned short* __restrict__ vt,
    int bm0, int bn0, int wm, int wn, int ln, int lq) {
  #pragma unroll
  for (int i = 0; i < 4; ++i) {
    const int row0 = bm0 + wm * 64 + i * 16 + lq * 4;
    #pragma unroll
    for (int j = 0; j < 4; ++j) {
      const int col = bn0 + wn * 64 + j * 16 + ln;
      const float bv = bias[col];
      if constexpr (MODE == 0) {
        #pragma unroll
        for (int r = 0; r < 4; ++r)
          store_out(&C[(size_t)(row0 + r) * ldc + col], acc[i][j][r] + bv);
      } else {
        if (bn0 < 2 * C_EMB) {  // q or k columns (wave-uniform per block)
          #pragma unroll
          for (int r = 0; r < 4; ++r)
            qk[(size_t)(row0 + r) * LQK + col] = f2b(acc[i][j][r] + bv);
        } else {                // v columns -> transposed store
          const int c2 = col - 2 * C_EMB;           // h*128 + d
          const int bb = row0 >> 11;                // batch
          const int t0 = row0 & (T_SEQ - 1);
          const int vrow = (bb * NH + (c2 >> 7)) * HD + (c2 & 127);
          ushort4 p;
          p.x = f2b(acc[i][j][0] + bv); p.y = f2b(acc[i][j][1] + bv);
          p.z = f2b(acc[i][j][2] + bv); p.w = f2b(acc[i][j][3] + bv);
          *(ushort4*)(vt + (size_t)vrow * T_SEQ + t0) = p;  // t0 % 4 == 0
        }
      }
    }
  }
}

// ---------------------------------------------------------------------------
// Tier A GEMM (m97 structure): C = A[M,K](bf16, lda) * Bt[N,K]^T(bf16) + bias.
// ---------------------------------------------------------------------------
template <int MODE, typename OutT>
__global__ __launch_bounds__(256) void gemm_bt(const unsigned short* __restrict__ A, int lda,
                                               const unsigned short* __restrict__ Bt,
                                               const float* __restrict__ bias,
                                               OutT* __restrict__ C, int ldc,
                                               unsigned short* __restrict__ qk,
                                               unsigned short* __restrict__ vt,
                                               int N, int K) {
  __shared__ __align__(16) unsigned short As[128 * 32];
  __shared__ __align__(16) unsigned short Bs[128 * 32];
  const int tid = threadIdx.x;
  const int wave = tid >> 6, lane = tid & 63;
  const int wm = wave >> 1, wn = wave & 1;
  const int ln = lane & 15, lq = lane >> 4;
  const int bm0 = blockIdx.y * 128, bn0 = blockIdx.x * 128;

  f32x4 acc[4][4];
  #pragma unroll
  for (int i = 0; i < 4; ++i)
    #pragma unroll
    for (int j = 0; j < 4; ++j) acc[i][j] = (f32x4){0.f, 0.f, 0.f, 0.f};

  const unsigned short* Ag = A  + (size_t)(bm0 + wave * 32 + (lane >> 2)) * lda + (lane & 3) * 8;
  const unsigned short* Bg = Bt + (size_t)(bn0 + wave * 32 + (lane >> 2)) * K   + (lane & 3) * 8;
  unsigned short* Al = As + wave * 1024 + lane * 8;
  unsigned short* Bl = Bs + wave * 1024 + lane * 8;

  for (int k0 = 0; k0 < K; k0 += 32) {
    async_cp16(Ag + k0, Al);
    async_cp16(Ag + k0 + 16 * lda, Al + 512);
    async_cp16(Bg + k0, Bl);
    async_cp16(Bg + k0 + 16 * K, Bl + 512);
    __syncthreads();
    bf16x8 af[4], bfv[4];
    #pragma unroll
    for (int i = 0; i < 4; ++i) {
      af[i]  = *(const bf16x8*)(As + (wm * 64 + i * 16 + ln) * 32 + lq * 8);
      bfv[i] = *(const bf16x8*)(Bs + (wn * 64 + i * 16 + ln) * 32 + lq * 8);
    }
    #pragma unroll
    for (int i = 0; i < 4; ++i)
      #pragma unroll
      for (int j = 0; j < 4; ++j)
        acc[i][j] = __builtin_amdgcn_mfma_f32_16x16x32_bf16(af[i], bfv[j], acc[i][j], 0, 0, 0);
    __syncthreads();
  }
  gemm_epilogue<MODE, OutT>(acc, bias, C, ldc, qk, vt, bm0, bn0, wm, wn, ln, lq);
}

// ---------------------------------------------------------------------------
// Tier B GEMM fallback (validated round-2 structure).
// ---------------------------------------------------------------------------
template <int MODE, typename AT, typename OutT>
__global__ __launch_bounds__(256) void gemm_any(const AT* __restrict__ A, int lda,
                                                const float* __restrict__ B, int ldb,
                                                const float* __restrict__ bias,
                                                OutT* __restrict__ C, int ldc,
                                                unsigned short* __restrict__ qk,
                                                unsigned short* __restrict__ vt,
                                                int N, int K) {
  __shared__ __align__(16) unsigned short As[128 * 32];
  __shared__ __align__(16) unsigned short Bs[128 * 32];
  __shared__ __align__(16) float Bstage[32 * 132];

  const int tid = threadIdx.x;
  const int wave = tid >> 6, lane = tid & 63;
  const int wm = wave >> 1, wn = wave & 1;
  const int ln = lane & 15, lq = lane >> 4;
  const int bm0 = blockIdx.y * 128, bn0 = blockIdx.x * 128;

  f32x4 acc[4][4];
  #pragma unroll
  for (int i = 0; i < 4; ++i)
    #pragma unroll
    for (int j = 0; j < 4; ++j) acc[i][j] = (f32x4){0.f, 0.f, 0.f, 0.f};

  for (int k0 = 0; k0 < K; k0 += 32) {
    #pragma unroll
    for (int j = 0; j < 4; ++j) {
      const int item = tid + j * 256;
      const int m = item >> 3;
      const int kf = (item & 7) * 4;
      *(ushort4*)(As + m * 32 + kf) = load4_bf16(A + (size_t)(bm0 + m) * lda + k0 + kf);
    }
    #pragma unroll
    for (int j = 0; j < 4; ++j) {
      const int item = tid + j * 256;
      const int kr = item >> 5;
      const int nf = (item & 31) * 4;
      *(float4*)(Bstage + kr * 132 + nf) =
          *(const float4*)(B + (size_t)(k0 + kr) * ldb + bn0 + nf);
    }
    __syncthreads();
    #pragma unroll
    for (int j = 0; j < 4; ++j) {
      const int item = tid + j * 256;
      const int n = item >> 3;
      const int kq = item & 7;
      const int k = kq * 4;
      ushort4 h4;
      h4.x = f2b(Bstage[(k + 0) * 132 + n]);
      h4.y = f2b(Bstage[(k + 1) * 132 + n]);
      h4.z = f2b(Bstage[(k + 2) * 132 + n]);
      h4.w = f2b(Bstage[(k + 3) * 132 + n]);
      *(ushort4*)(Bs + n * 32 + (((kq >> 1) ^ (n & 3)) << 3) + ((kq & 1) << 2)) = h4;
    }
    __syncthreads();
    bf16x8 af[4], bfv[4];
    #pragma unroll
    for (int i = 0; i < 4; ++i) {
      af[i] = *(const bf16x8*)(As + (wm * 64 + i * 16 + ln) * 32 + lq * 8);
      const int n = wn * 64 + i * 16 + ln;
      bfv[i] = *(const bf16x8*)(Bs + n * 32 + ((lq ^ (n & 3)) << 3));
    }
    #pragma unroll
    for (int i = 0; i < 4; ++i)
      #pragma unroll
      for (int j = 0; j < 4; ++j)
        acc[i][j] = __builtin_amdgcn_mfma_f32_16x16x32_bf16(af[i], bfv[j], acc[i][j], 0, 0, 0);
    __syncthreads();
  }
  gemm_epilogue<MODE, OutT>(acc, bias, C, ldc, qk, vt, bm0, bn0, wm, wn, ln, lq);
}

// ---------------------------------------------------------------- prep (Tier A)
__global__ __launch_bounds__(256) void cast_x_bf16(const float4* __restrict__ in,
                                                   ushort4* __restrict__ out, int n4) {
  int i = blockIdx.x * 256 + threadIdx.x;
  if (i < n4) {
    float4 v = in[i];
    ushort4 o; o.x = f2b(v.x); o.y = f2b(v.y); o.z = f2b(v.z); o.w = f2b(v.w);
    out[i] = o;
  }
}

__global__ __launch_bounds__(256) void transpose_cast(const float* __restrict__ in,
                                                      unsigned short* __restrict__ out,
                                                      int R, int Cc) {
  __shared__ float t[32][33];
  const int bx = blockIdx.x * 32, by = blockIdx.y * 32;
  const int tx = threadIdx.x & 31, ty = threadIdx.x >> 5;
  #pragma unroll
  for (int j = 0; j < 32; j += 8)
    t[ty + j][tx] = in[(size_t)(by + ty + j) * Cc + bx + tx];
  __syncthreads();
  #pragma unroll
  for (int j = 0; j < 32; j += 8)
    out[(size_t)(bx + ty + j) * R + by + tx] = f2b(t[tx][ty + j]);
}

// ---------------------------------------------------------------------------
// Flash attention: transposed-S, max-free softmax, 8-wave (512-thread) blocks.
// grid (16, NH, B). Block covers 128 queries [128j, 128j+128); wave w owns 16
// queries (one 16-q tile — round-4 register footprint, NO double tile: that
// spilled in round 5). All 8 waves share each staged K/V tile, halving
// staging traffic and barrier rounds per query vs 4-wave blocks.
// Per 64-key iteration: S^T = K Q^T (K from LDS, Q in regs); p = exp2(s*c)
// with NO running max (scores bounded -> no overflow; l accumulated per lane,
// reduced once after the loop); O^T += V^T P^T via K=16 MFMA, P in registers.
// Per-wave skip of fully-masked key blocks; mask on diagonal blocks only.
// j mapping: b=0 longest-first, b=1 shortest-first -> paired blocks on a CU
// sum to constant work (heuristic only; correctness unaffected).
// y written into the q-columns of qk (race-free as before).
// ---------------------------------------------------------------------------
__global__ __launch_bounds__(512, 4) void attn_st(unsigned short* __restrict__ qk,
                                                  const unsigned short* __restrict__ vt) {
  // staging: Ks[64][136] (17408) + VTs[128][72] (9216) = 17920 shorts;
  // epilogue reuses the same pool as Os[128][136] (17408).
  __shared__ __align__(16) unsigned short smem[17920];
  unsigned short* Ks  = smem;            // K tile [key][d], pad 136
  unsigned short* VTs = smem + 64 * 136; // V^T tile [d][key], pad 72

  const int tid = threadIdx.x;
  const int w = tid >> 6, lane = tid & 63;
  const int ln = lane & 15, lq = lane >> 4;
  const int b = blockIdx.z, h = blockIdx.y;
  const int j = (b == 0) ? (15 - (int)blockIdx.x) : (int)blockIdx.x;
  const int qb0 = j * 128;
  // 1/sqrt(128) * log2(e): scale folded into exp2 argument
  const float EXPSC = 0.08838834764831845f * 1.4426950408889634f;

  // Q fragments (B-operand: n=ln=query, k=lq*8..) straight from global, once
  const int wq0 = qb0 + w * 16;
  const int qg = wq0 + ln;
  const unsigned short* Qp = qk + (size_t)(b * T_SEQ + qg) * LQK + h * HD + lq * 8;
  bf16x8 bq[4];
  #pragma unroll
  for (int ks = 0; ks < 4; ++ks) bq[ks] = *(const bf16x8*)(Qp + ks * 32);

  f32x4 ot[8];  // O^T accum: regs = d = dt*16+lq*4+r, col = query ln
  #pragma unroll
  for (int dt = 0; dt < 8; ++dt) ot[dt] = (f32x4){0.f, 0.f, 0.f, 0.f};
  float l_i = 0.f;

  const int kbmax = 2 * j + 1;
  for (int kb = 0; kb <= kbmax; ++kb) {
    __syncthreads();  // prev iter's LDS reads complete
    #pragma unroll
    for (int jj = 0; jj < 2; ++jj) {      // K tile: 64 keys x 128 d (1024 uint4)
      const int s = tid + jj * 512;
      const int row = s >> 4, c8 = s & 15;
      *(uint4*)(Ks + row * 136 + c8 * 8) =
          *(const uint4*)(qk + (size_t)(b * T_SEQ + kb * 64 + row) * LQK + C_EMB + h * HD + c8 * 8);
    }
    #pragma unroll
    for (int jj = 0; jj < 2; ++jj) {      // V^T tile: 128 d x 64 keys (1024 uint4)
      const int s = tid + jj * 512;
      const int row = s >> 3, c8 = s & 7;
      *(uint4*)(VTs + row * 72 + c8 * 8) =
          *(const uint4*)(vt + ((size_t)(b * NH + h) * HD + row) * T_SEQ + kb * 64 + c8 * 8);
    }
    __syncthreads();

    if (kb * 64 <= wq0 + 15) {            // wave has unmasked work this block
      const bool diag = (kb * 64 + 63 > wq0);

      // ---- S^T = K Q^T
      f32x4 st[4];
      #pragma unroll
      for (int kt = 0; kt < 4; ++kt) {
        st[kt] = (f32x4){0.f, 0.f, 0.f, 0.f};
        #pragma unroll
        for (int ks = 0; ks < 4; ++ks) {
          bf16x8 ak = *(const bf16x8*)(Ks + (kt * 16 + ln) * 136 + ks * 32 + lq * 8);
          st[kt] = __builtin_amdgcn_mfma_f32_16x16x32_bf16(ak, bq[ks], st[kt], 0, 0, 0);
        }
      }

      // ---- max-free softmax: p = exp2(s*EXPSC); zero masked; accumulate l
      short4v pf[4];
      #pragma unroll
      for (int kt = 0; kt < 4; ++kt)
        #pragma unroll
        for (int r = 0; r < 4; ++r) {
          float p = __builtin_exp2f(st[kt][r] * EXPSC);
          if (diag && (kb * 64 + kt * 16 + lq * 4 + r > qg)) p = 0.f;
          l_i += p;
          pf[kt][r] = (short)f2b(p);
        }

      // ---- O^T += V^T P^T : K=16 MFMA, P straight from registers
      #pragma unroll
      for (int kt = 0; kt < 4; ++kt)
        #pragma unroll
        for (int dt = 0; dt < 8; ++dt) {
          short4v av = *(const short4v*)(VTs + (dt * 16 + ln) * 72 + kt * 16 + lq * 4);
          ot[dt] = __builtin_amdgcn_mfma_f32_16x16x16bf16_1k(av, pf[kt], ot[dt], 0, 0, 0);
        }
    }
  }

  // ---- final l reduction across the 4 partner lanes (once)
  l_i += __shfl_xor(l_i, 16);
  l_i += __shfl_xor(l_i, 32);
  const float inv = 1.f / l_i;

  // ---- epilogue: O^T -> O via LDS (smem as Os[128][136]), coalesced store
  __syncthreads();
  #pragma unroll
  for (int dt = 0; dt < 8; ++dt) {
    ushort4 p4;
    p4.x = f2b(ot[dt][0] * inv); p4.y = f2b(ot[dt][1] * inv);
    p4.z = f2b(ot[dt][2] * inv); p4.w = f2b(ot[dt][3] * inv);
    *(ushort4*)(smem + (w * 16 + ln) * 136 + dt * 16 + lq * 4) = p4;
  }
  __syncthreads();
  #pragma unroll
  for (int jj = 0; jj < 4; ++jj) {        // 128 rows x 16 uint4 = 2048 items
    const int s = tid + jj * 512;
    const int row = s >> 4, c8 = s & 15;
    *(uint4*)(qk + (size_t)(b * T_SEQ + qb0 + row) * LQK + h * HD + c8 * 8) =
        *(const uint4*)(smem + row * 136 + c8 * 8);
  }
}

// ---------------------------------------------------------------- launch
extern "C" void kernel_launch(void* const* d_in, const int* in_sizes, int n_in,
                              void* d_out, int out_size, void* d_ws, size_t ws_size,
                              hipStream_t stream) {
  (void)in_sizes; (void)n_in; (void)out_size;
  const float* x      = (const float*)d_in[0];
  const float* W_attn = (const float*)d_in[1];
  const float* b_attn = (const float*)d_in[2];
  const float* W_proj = (const float*)d_in[3];
  const float* b_proj = (const float*)d_in[4];
  float* out = (float*)d_out;

  char* ws = (char*)d_ws;
  unsigned short* qk = (unsigned short*)(ws);                  // 32 MiB [4096][4096]
  unsigned short* vt = (unsigned short*)(ws + 33554432);       // 16 MiB [B*NH*HD][T]
  unsigned short* xb  = (unsigned short*)(ws + 50331648);      // 16 MiB x bf16
  unsigned short* WaT = (unsigned short*)(ws + 67108864);      // 24 MiB W_attn^T bf16
  unsigned short* WpT = (unsigned short*)(ws + 92274688);      // 8  MiB W_proj^T bf16
  const bool tierA = (ws_size >= 100663296);                   // 96 MiB

  if (tierA) {
    const int n_x = M_ROWS * C_EMB;
    cast_x_bf16<<<n_x / 4 / 256, 256, 0, stream>>>((const float4*)x, (ushort4*)xb, n_x / 4);
    transpose_cast<<<dim3(N_QKV / 32, C_EMB / 32), 256, 0, stream>>>(W_attn, WaT, C_EMB, N_QKV);
    transpose_cast<<<dim3(C_EMB / 32, C_EMB / 32), 256, 0, stream>>>(W_proj, WpT, C_EMB, C_EMB);
    gemm_bt<1, unsigned short><<<dim3(N_QKV / 128, M_ROWS / 128), 256, 0, stream>>>(
        xb, C_EMB, WaT, b_attn, (unsigned short*)nullptr, 0, qk, vt, N_QKV, C_EMB);
  } else {
    gemm_any<1, float, unsigned short><<<dim3(N_QKV / 128, M_ROWS / 128), 256, 0, stream>>>(
        x, C_EMB, W_attn, N_QKV, b_attn, (unsigned short*)nullptr, 0, qk, vt, N_QKV, C_EMB);
  }

  attn_st<<<dim3(16, NH, B_SZ), 512, 0, stream>>>(qk, vt);

  if (tierA) {
    gemm_bt<0, float><<<dim3(C_EMB / 128, M_ROWS / 128), 256, 0, stream>>>(
        qk, LQK, WpT, b_proj, out, C_EMB, nullptr, nullptr, C_EMB, C_EMB);
  } else {
    gemm_any<0, unsigned short, float><<<dim3(C_EMB / 128, M_ROWS / 128), 256, 0, stream>>>(
        qk, LQK, W_proj, C_EMB, b_proj, out, C_EMB, nullptr, nullptr, C_EMB, C_EMB);
  }
}